// Round 13
// baseline (451.918 us; speedup 1.0000x reference)
//
#include <hip/hip_runtime.h>
#include <math.h>

typedef short bf16x8 __attribute__((ext_vector_type(8)));
typedef float f32x4 __attribute__((ext_vector_type(4)));

#define S128 0.08838834764831845f   /* 1/sqrt(128) */
#define S256I 0.0625f               /* 1/sqrt(256) */
#define NN_NODES 16000

// ws layout (bytes)
#define WS_COUNTS   16448000            /* int[16000] (node arrays occupy [0,16448000)) */
#define WS_OFFSETS  (WS_COUNTS + 64000)
#define WS_CURSOR   (WS_OFFSETS + 64000)
#define WS_INV      (WS_CURSOR + 64000) /* int[256000]: e -> sorted pos */
#define WS_W1 (WS_INV + 1024000)        /* W1T [128][256] bf16 unswizzled */
#define WS_W2 (WS_W1 + 65536)           /* W2T [128][128] bf16 unswizzled */
#define WS_W3 (WS_W2 + 32768)           /* W3T [128][128] bf16 unswizzled */
#define WS_WO (WS_W3 + 32768)           /* WoutT [64][128] bf16 PRE-SWIZZLED (LDS-staged) */
#define WS_WE (WS_WO + 16384)           /* WenvT [128][128] bf16 unswizzled (reg-loaded) */
#define WS_VECM (WS_WE + 32768)         /* float4[256000]: sorted (vx,vy,vz,m) */
#define WS_XMB  (WS_VECM + 4096000)     /* bf16 xm [E][128] SORTED order, 65.5MB */
#define WS_ORDER (WS_XMB + 65536000)    /* int[256000]: sorted pos -> e */

// ---- host-side constant: SILU_C exactly as the reference computes it ----
static float compute_inv_silu_c() {
    double sum = 0.0, prev = 0.0;
    const double dz = 24.0 / 100000.0;
    for (int i = 0; i <= 100000; ++i) {
        double z = -12.0 + dz * (double)i;
        double pdf = exp(-0.5 * z * z) * 0.3989422804014327;
        double s = z / (1.0 + exp(-z));
        double f = s * s * pdf;
        if (i) sum += 0.5 * (prev + f) * dz;
        prev = f;
    }
    return (float)(1.0 / sqrt(sum));
}
static const float INV_SILU_C = compute_inv_silu_c();

// ---- device helpers ----
__device__ __forceinline__ unsigned int packbf(float a, float b) {
    union { float f; unsigned int u; } ca, cb;
    ca.f = a; cb.f = b;
    unsigned int ua = ca.u + (0x7fffu + ((ca.u >> 16) & 1u));
    unsigned int ub = cb.u + (0x7fffu + ((cb.u >> 16) & 1u));
    return (ua >> 16) | (ub & 0xffff0000u);
}
__device__ __forceinline__ unsigned short bf16r(float v) {
    union { float f; unsigned int u; } c; c.f = v;
    return (unsigned short)((c.u + (0x7fffu + ((c.u >> 16) & 1u))) >> 16);
}
__device__ __forceinline__ float bflo(unsigned int u) { return __uint_as_float(u << 16); }
__device__ __forceinline__ float bfhi(unsigned int u) { return __uint_as_float(u & 0xffff0000u); }
// full-width swizzle for 256B-stride rows: spreads 16 rows across all bank groups
__device__ __forceinline__ int swz(int row, int b) { return b ^ ((row & 15) << 4); }
__device__ __forceinline__ float nsilu(float v, float ic) {
    return v / (1.0f + __expf(-v)) * ic;
}

// =====================================================================
// k_wprep: bf16-quantize + transpose weights into ws; zero counts[].
// =====================================================================
__global__ __launch_bounds__(256) void k_wprep(
    const float* __restrict__ W1, const float* __restrict__ W2,
    const float* __restrict__ W3, const float* __restrict__ Wout,
    const float* __restrict__ Wenv, char* __restrict__ wsb)
{
    const int t = blockIdx.x * 256 + threadIdx.x;   // 32768 threads
    if (t < NN_NODES) ((int*)(wsb + WS_COUNTS))[t] = 0;
    if (t < 32768) {  // W1T[128][256]
        int n = t & 127, k = t >> 7;
        *(unsigned short*)(wsb + WS_W1 + n * 512 + k * 2) =
            bf16r(W1[k * 128 + n] * S256I);
    }
    if (t < 16384) {  // W2T, W3T [128][128]
        int n = t & 127, k = t >> 7;
        *(unsigned short*)(wsb + WS_W2 + n * 256 + k * 2) =
            bf16r(W2[k * 128 + n] * S128);
        *(unsigned short*)(wsb + WS_W3 + n * 256 + k * 2) =
            bf16r(W3[k * 128 + n] * S128);
    }
    if (t < 16384) {  // WenvT[128][128], interleaved row perm (w0/w1 pairs)
        int j = t & 127, k = t >> 7;
        int c = (j & 1) ? 64 + (j >> 1) : (j >> 1);
        *(unsigned short*)(wsb + WS_WE + j * 256 + k * 2) =
            bf16r(Wenv[k * 128 + c] * S128);
    }
    if (t < 8192) {   // WoutT[64][128] pre-swizzled (full-width)
        int o = t & 63, uu = t >> 6;
        *(unsigned short*)(wsb + WS_WO + o * 256 + ((uu * 2) ^ ((o & 15) << 4))) =
            bf16r(Wout[uu * 64 + o] * S128);
    }
}

// =====================================================================
// sort-by-sender chain
// =====================================================================
__global__ __launch_bounds__(1024) void k_hist(
    const int* __restrict__ senders, int* __restrict__ counts, int E)
{
    const int e = blockIdx.x * 1024 + threadIdx.x;
    if (e < E) atomicAdd(&counts[senders[e]], 1);
}

__global__ __launch_bounds__(1024) void k_scan(
    const int* __restrict__ counts, int* __restrict__ offsets,
    int* __restrict__ cursor)
{
    __shared__ int part[1024];
    const int t = threadIdx.x;
    const int s0 = t * 16;
    const int s1 = (s0 + 16 < NN_NODES) ? s0 + 16 : NN_NODES;
    int s = 0;
    for (int i = s0; i < s1; ++i) s += counts[i];
    part[t] = s;
    __syncthreads();
    for (int off = 1; off < 1024; off <<= 1) {
        int v = part[t];
        if (t >= off) v += part[t - off];
        __syncthreads();
        part[t] = v;
        __syncthreads();
    }
    int run = t ? part[t - 1] : 0;
    for (int i = s0; i < s1; ++i) {
        offsets[i] = run; cursor[i] = run; run += counts[i];
    }
}

__global__ __launch_bounds__(1024) void k_binfill(
    const int* __restrict__ senders, const float* __restrict__ vectors,
    const float* __restrict__ m, int* __restrict__ cursor,
    int* __restrict__ inv, int* __restrict__ order,
    float4* __restrict__ vecm, int E)
{
    const int e = blockIdx.x * 1024 + threadIdx.x;
    if (e < E) {
        const int p = atomicAdd(&cursor[senders[e]], 1);
        inv[e] = p;
        order[p] = e;
        float4 vm;
        vm.x = vectors[(size_t)e * 3 + 0];
        vm.y = vectors[(size_t)e * 3 + 1];
        vm.z = vectors[(size_t)e * 3 + 2];
        vm.w = m[e];
        vecm[p] = vm;
    }
}

// =====================================================================
// k_env: w = (x*m) @ WenvT via MFMA. 128 edges/block, 32KB LDS.
// Exports bf16 xm AND w rows at SORTED positions.
// =====================================================================
__global__ __launch_bounds__(512) void k_env(
    const float* __restrict__ x, const float* __restrict__ m,
    const char* __restrict__ wsb, const int* __restrict__ inv,
    char* __restrict__ wout, char* __restrict__ xmb, int E)
{
    __shared__ char lds[32768];  // xm [128][256B] swz; reused for bf16 results
    const int tid = threadIdx.x, l = tid & 63, wid = tid >> 6;
    const int lr = l & 15, lg = l >> 4;
    const int n0 = wid * 16;

    // WenvT fragments for this wave's 16 columns (loop-invariant)
    bf16x8 B[4];
    #pragma unroll
    for (int kk = 0; kk < 4; ++kk)
        B[kk] = *(const bf16x8*)(wsb + WS_WE + (n0 + lr) * 256 + kk * 64 + lg * 16);

    const int eb = blockIdx.x * 128;
    {   // xm tile: 4 threads/edge
        const int el = tid >> 2, q = tid & 3;
        const int e = eb + el;
        if (e < E) {
            const float mv = m[e];
            const float4* xp = (const float4*)&x[(size_t)e * 128 + q * 32];
            #pragma unroll
            for (int j = 0; j < 4; ++j) {
                float4 A = xp[2 * j], Bv = xp[2 * j + 1];
                int4 w;
                w.x = packbf(A.x * mv, A.y * mv); w.y = packbf(A.z * mv, A.w * mv);
                w.z = packbf(Bv.x * mv, Bv.y * mv); w.w = packbf(Bv.z * mv, Bv.w * mv);
                *(int4*)(lds + el * 256 + swz(el, q * 64 + j * 16)) = w;
            }
        } else {
            const int4 z = {0, 0, 0, 0};
            #pragma unroll
            for (int j = 0; j < 4; ++j)
                *(int4*)(lds + el * 256 + swz(el, q * 64 + j * 16)) = z;
        }
    }
    __syncthreads();

    {   // export xm bf16 at SORTED position p = inv[e]
        const int el = tid >> 2, q = tid & 3;
        const int e = eb + el;
        if (e < E) {
            const int p = inv[e];
            int4* d = (int4*)(xmb + (size_t)p * 256 + q * 64);
            #pragma unroll
            for (int j = 0; j < 4; ++j)
                d[j] = *(int4*)(lds + el * 256 + swz(el, q * 64 + j * 16));
        }
    }

    f32x4 acc[8];
    #pragma unroll
    for (int a = 0; a < 8; ++a) acc[a] = (f32x4){0.f, 0.f, 0.f, 0.f};

    #pragma unroll
    for (int kk = 0; kk < 4; ++kk) {
        const int kb = kk * 64 + lg * 16;
        #pragma unroll
        for (int mt = 0; mt < 8; ++mt) {
            const int row = mt * 16 + lr;
            bf16x8 a = *(const bf16x8*)(lds + row * 256 + swz(row, kb));
            acc[mt] = __builtin_amdgcn_mfma_f32_16x16x32_bf16(a, B[kk], acc[mt], 0, 0, 0);
        }
    }
    __syncthreads();   // all A-reads done; reuse buffer for results

    #pragma unroll
    for (int mt = 0; mt < 8; ++mt)
        #pragma unroll
        for (int r = 0; r < 4; ++r) {
            const int row = mt * 16 + lg * 4 + r;
            *(unsigned short*)(lds + row * 256 + swz(row, (n0 + lr) * 2)) =
                bf16r(acc[mt][r]);
        }
    __syncthreads();

    {   // copy-out to SORTED position p = inv[e]
        const int el = tid >> 2, q = tid & 3;
        const int e = eb + el;
        if (e < E) {
            const int p = inv[e];
            int4* d = (int4*)(wout + (size_t)p * 256 + q * 64);
            #pragma unroll
            for (int j = 0; j < 4; ++j)
                d[j] = *(int4*)(lds + el * 256 + swz(el, q * 64 + j * 16));
        }
    }
}

// =====================================================================
// k_gather: one wave per node; STREAMING reads of sorted w rows and
// vecm; write node accumulators once (no atomics).
// =====================================================================
__global__ __launch_bounds__(256) void k_gather(
    const char* __restrict__ wvb, const float4* __restrict__ vecm,
    const int* __restrict__ counts, const int* __restrict__ offsets,
    float* __restrict__ node_cnt, float* __restrict__ node_s,
    float* __restrict__ node_v)
{
    const int l = threadIdx.x & 63, wid = threadIdx.x >> 6;
    const int n = blockIdx.x * 4 + wid;
    if (n >= NN_NODES) return;
    const int cnt = counts[n], base = offsets[n];

    float as = 0.f, a0 = 0.f, a1 = 0.f, a2 = 0.f, am = 0.f;
    #pragma unroll 4
    for (int i = 0; i < cnt; ++i) {
        const unsigned int wv =
            *(const unsigned int*)(wvb + (size_t)(base + i) * 256 + l * 4);
        const float4 vm = vecm[base + i];
        const float rn = 1.7320508075688772f /
                         sqrtf(vm.x * vm.x + vm.y * vm.y + vm.z * vm.z);
        const float w0 = bflo(wv) * vm.w;
        const float c1 = bfhi(wv) * vm.w * rn;
        as += w0; am += vm.w;
        a0 += c1 * vm.x; a1 += c1 * vm.y; a2 += c1 * vm.z;
    }
    if (l == 0) node_cnt[n] = am;
    node_s[(size_t)n * 64 + l] = as;
    float* nv = &node_v[((size_t)n * 64 + l) * 3];
    nv[0] = a0; nv[1] = a1; nv[2] = a2;
}

// =====================================================================
// k_fuse: merged prep_vout + MLP, processing edges in SENDER-SORTED
// order: block handles sorted positions [64b, 64b+64) -> consecutive
// edges share senders -> node gather is L1/L2-hot (~4 distinct nodes
// per block instead of 64 random ones). V/out accesses are per-edge
// granules (256-768B), coalesced within each granule.
// LDS map: [0:48K) vin -> Vout f32 stage -> {xcatLo,h@32K} -> g@0 -> out
//          [48K:64K) WoutT (pre-swizzled)   [64K:80K) xcatHi (s_a|s_b)
// =====================================================================
__global__ __launch_bounds__(512, 4) void k_fuse(
    const float* __restrict__ V, const int* __restrict__ senders,
    const float* __restrict__ node_cnt, const float* __restrict__ node_s,
    const float* __restrict__ node_v, const char* __restrict__ wsb,
    const char* __restrict__ xmb, const float* __restrict__ ug,
    const int* __restrict__ order,
    float* __restrict__ out_x, float* __restrict__ out_v,
    float inv_c, int E)
{
    __shared__ char lds[81920];
    const int tid = threadIdx.x, l = tid & 63, wid = tid >> 6;
    const int lr = l & 15, lg = l >> 4;
    const int pbase = blockIdx.x * 64;

    {   // stage WoutT (pre-swizzled) -> [48K:64K)
        const int4* src = (const int4*)(wsb + WS_WO);
        ((int4*)(lds + 49152))[tid * 2]     = src[tid * 2];
        ((int4*)(lds + 49152))[tid * 2 + 1] = src[tid * 2 + 1];
    }

    // ---- phase A: per-edge gather (sorted order); vin + sab stash ----
    #pragma unroll 2
    for (int i = 0; i < 8; ++i) {
        const int el = wid * 8 + i;
        const int p  = pbase + el;
        float Vs = 0.f, Vv0 = 0.f, Vv1 = 0.f, Vv2 = 0.f;
        float wYs = 0.f, wv0 = 0.f, wv1 = 0.f, wv2 = 0.f;
        if (p < E) {
            const int e = order[p];
            Vs = V[(size_t)e * 256 + l];
            const float* vp = &V[(size_t)e * 256 + 64 + l * 3];
            Vv0 = vp[0]; Vv1 = vp[1]; Vv2 = vp[2];
            const int sn = senders[e];
            const float rden = 1.0f / (node_cnt[sn] + 1e-5f);
            wYs = node_s[(size_t)sn * 64 + l] * rden;
            const float* nvp = &node_v[((size_t)sn * 64 + l) * 3];
            wv0 = nvp[0] * rden; wv1 = nvp[1] * rden; wv2 = nvp[2] * rden;
        }
        // s_a/s_b straight into phase-B xcatHi layout (swizzled, 256B rows)
        *(unsigned short*)(lds + 65536 + el * 256 + swz(el, l * 2)) =
            bf16r(wYs * Vs);
        *(unsigned short*)(lds + 65536 + el * 256 + swz(el, 128 + l * 2)) =
            bf16r((wv0 * Vv0 + wv1 * Vv1 + wv2 * Vv2) * 0.57735026918962576f);
        const float vvk[3] = {Vv0, Vv1, Vv2};
        const float wvk[3] = {wv0, wv1, wv2};
        #pragma unroll
        for (int k = 0; k < 3; ++k) {
            const int row = el * 3 + k;
            *(unsigned short*)(lds + row * 256 + swz(row, l * 2))       = bf16r(wYs * vvk[k]);
            *(unsigned short*)(lds + row * 256 + swz(row, 128 + l * 2)) = bf16r(wvk[k] * Vs);
        }
    }
    __syncthreads();

    // ---- V_out GEMM: waves 4x2; wave = 3 m-tiles x 2 n-tiles ----
    {
        const int wm = wid & 3, wn = wid >> 2;
        const int m0 = wm * 48, n0v = wn * 32;
        f32x4 acc[3][2];
        #pragma unroll
        for (int a = 0; a < 3; ++a)
            #pragma unroll
            for (int b = 0; b < 2; ++b) acc[a][b] = (f32x4){0.f, 0.f, 0.f, 0.f};

        #pragma unroll
        for (int kk = 0; kk < 4; ++kk) {
            const int kb = kk * 64 + lg * 16;
            bf16x8 a0 = *(const bf16x8*)(lds + (m0 + lr) * 256      + swz(m0 + lr, kb));
            bf16x8 a1 = *(const bf16x8*)(lds + (m0 + 16 + lr) * 256 + swz(m0 + 16 + lr, kb));
            bf16x8 a2 = *(const bf16x8*)(lds + (m0 + 32 + lr) * 256 + swz(m0 + 32 + lr, kb));
            bf16x8 b0 = *(const bf16x8*)(lds + 49152 + (n0v + lr) * 256      + swz(n0v + lr, kb));
            bf16x8 b1 = *(const bf16x8*)(lds + 49152 + (n0v + 16 + lr) * 256 + swz(n0v + 16 + lr, kb));
            acc[0][0] = __builtin_amdgcn_mfma_f32_16x16x32_bf16(a0, b0, acc[0][0], 0, 0, 0);
            acc[0][1] = __builtin_amdgcn_mfma_f32_16x16x32_bf16(a0, b1, acc[0][1], 0, 0, 0);
            acc[1][0] = __builtin_amdgcn_mfma_f32_16x16x32_bf16(a1, b0, acc[1][0], 0, 0, 0);
            acc[1][1] = __builtin_amdgcn_mfma_f32_16x16x32_bf16(a1, b1, acc[1][1], 0, 0, 0);
            acc[2][0] = __builtin_amdgcn_mfma_f32_16x16x32_bf16(a2, b0, acc[2][0], 0, 0, 0);
            acc[2][1] = __builtin_amdgcn_mfma_f32_16x16x32_bf16(a2, b1, acc[2][1], 0, 0, 0);
        }
        __syncthreads();   // all vin reads done; reuse [0:48K) as f32 stage

        #pragma unroll
        for (int mt = 0; mt < 3; ++mt)
            #pragma unroll
            for (int nt = 0; nt < 2; ++nt)
                #pragma unroll
                for (int r = 0; r < 4; ++r) {
                    const int mm = m0 + mt * 16 + lg * 4 + r;
                    const int el2 = mm / 3, kd = mm - el2 * 3;
                    const int o = n0v + nt * 16 + lr;
                    *(float*)(lds + el2 * 768 + (o * 3 + kd) * 4) = acc[mt][nt][r];
                }
    }
    __syncthreads();
    {   // per-edge copy-out (scattered 768B granules via order[])
        const int el = tid >> 3, q = tid & 7;
        const int p = pbase + el;
        if (p < E) {
            const int e = order[p];
            const int4* s = (const int4*)(lds + el * 768 + q * 96);
            int4* d = (int4*)(out_v + (size_t)e * 192 + q * 24);
            #pragma unroll
            for (int j = 0; j < 6; ++j) d[j] = s[j];
        }
    }
    __syncthreads();   // copy-out reads done; [0:48K) free for phase B

    // ---- phase B: MLP ----
    // xcatLo [64][256B] @0 (xm, SORTED->streaming); xcatHi @64K; h @32K
    const int n0 = wid * 16;
    bf16x8 B1[8];
    #pragma unroll
    for (int kk = 0; kk < 8; ++kk)
        B1[kk] = *(const bf16x8*)(wsb + WS_W1 + (n0 + lr) * 512 + kk * 64 + lg * 16);

    {   // xm -> xcatLo: 8 threads/edge (xmb is sorted -> linear read)
        const int el = tid >> 3, q = tid & 7;
        const int p = pbase + el;
        int4 x0, x1;
        if (p < E) {
            const int4* xp = (const int4*)(xmb + (size_t)p * 256 + q * 32);
            x0 = xp[0]; x1 = xp[1];
        } else {
            x0 = (int4){0, 0, 0, 0}; x1 = (int4){0, 0, 0, 0};
        }
        *(int4*)(lds + el * 256 + swz(el, q * 32))      = x0;
        *(int4*)(lds + el * 256 + swz(el, q * 32 + 16)) = x1;
    }
    __syncthreads();

    // stage 1: xcat[64x256] @ W1T  (cols 0-127 @0, cols 128-255 @64K)
    f32x4 a1[4];
    #pragma unroll
    for (int a = 0; a < 4; ++a) a1[a] = (f32x4){0.f, 0.f, 0.f, 0.f};
    #pragma unroll
    for (int kk = 0; kk < 8; ++kk) {
        const int base = (kk < 4) ? 0 : 65536;
        const int kb = (kk & 3) * 64 + lg * 16;
        #pragma unroll
        for (int mt = 0; mt < 4; ++mt) {
            const int row = mt * 16 + lr;
            bf16x8 a = *(const bf16x8*)(lds + base + row * 256 + swz(row, kb));
            a1[mt] = __builtin_amdgcn_mfma_f32_16x16x32_bf16(a, B1[kk], a1[mt], 0, 0, 0);
        }
    }

    bf16x8 B2[4], B3[4];
    #pragma unroll
    for (int kk = 0; kk < 4; ++kk) {
        B2[kk] = *(const bf16x8*)(wsb + WS_W2 + (n0 + lr) * 256 + kk * 64 + lg * 16);
        B3[kk] = *(const bf16x8*)(wsb + WS_W3 + (n0 + lr) * 256 + kk * 64 + lg * 16);
    }

    // write h (bf16) to [32K:48K)
    #pragma unroll
    for (int mt = 0; mt < 4; ++mt)
        #pragma unroll
        for (int r = 0; r < 4; ++r) {
            const int row = mt * 16 + lg * 4 + r;
            *(unsigned short*)(lds + 32768 + row * 256 + swz(row, (n0 + lr) * 2)) =
                bf16r(nsilu(a1[mt][r], inv_c));
        }
    __syncthreads();

    // stage 2: h @ W2T
    f32x4 a2[4];
    #pragma unroll
    for (int a = 0; a < 4; ++a) a2[a] = (f32x4){0.f, 0.f, 0.f, 0.f};
    #pragma unroll
    for (int kk = 0; kk < 4; ++kk) {
        const int kb = kk * 64 + lg * 16;
        #pragma unroll
        for (int mt = 0; mt < 4; ++mt) {
            const int row = mt * 16 + lr;
            bf16x8 a = *(const bf16x8*)(lds + 32768 + row * 256 + swz(row, kb));
            a2[mt] = __builtin_amdgcn_mfma_f32_16x16x32_bf16(a, B2[kk], a2[mt], 0, 0, 0);
        }
    }
    // write g (bf16) into [0:16K) — xcatLo reads finished (h barrier)
    #pragma unroll
    for (int mt = 0; mt < 4; ++mt)
        #pragma unroll
        for (int r = 0; r < 4; ++r) {
            const int row = mt * 16 + lg * 4 + r;
            *(unsigned short*)(lds + row * 256 + swz(row, (n0 + lr) * 2)) =
                bf16r(nsilu(a2[mt][r], inv_c));
        }
    __syncthreads();

    // stage 3: g @ W3T
    f32x4 a3[4];
    #pragma unroll
    for (int a = 0; a < 4; ++a) a3[a] = (f32x4){0.f, 0.f, 0.f, 0.f};
    #pragma unroll
    for (int kk = 0; kk < 4; ++kk) {
        const int kb = kk * 64 + lg * 16;
        #pragma unroll
        for (int mt = 0; mt < 4; ++mt) {
            const int row = mt * 16 + lr;
            bf16x8 a = *(const bf16x8*)(lds + row * 256 + swz(row, kb));
            a3[mt] = __builtin_amdgcn_mfma_f32_16x16x32_bf16(a, B3[kk], a3[mt], 0, 0, 0);
        }
    }
    __syncthreads();   // all g reads done; reuse [0:32K) for f32 out tiles

    // out staging: cols 0-63 -> outLo @0, 64-127 -> outHi @16K (256B rows)
    {
        const int base = (n0 < 64) ? 0 : 16384;
        const int colb = n0 & 63;
        #pragma unroll
        for (int mt = 0; mt < 4; ++mt)
            #pragma unroll
            for (int r = 0; r < 4; ++r) {
                const int row = mt * 16 + lg * 4 + r;
                *(float*)(lds + base + row * 256 + swz(row, (colb + lr) * 4)) = a3[mt][r];
            }
    }
    __syncthreads();

    {   // copy-out with u scaling (scattered 512B granules via order[])
        const int el = tid >> 3, q = tid & 7;
        const int p = pbase + el;
        if (p < E) {
            const int e = order[p];
            const float uu = ug[e];
            #pragma unroll
            for (int j = 0; j < 4; ++j) {
                const int b = q * 64 + j * 16;       // byte in 512B logical row
                const int base = (b < 256) ? 0 : 16384;
                int4 v = *(int4*)(lds + base + el * 256 + swz(el, b & 255));
                float4 f;
                f.x = __int_as_float(v.x) * uu; f.y = __int_as_float(v.y) * uu;
                f.z = __int_as_float(v.z) * uu; f.w = __int_as_float(v.w) * uu;
                *(float4*)(&out_x[(size_t)e * 128 + q * 16 + j * 4]) = f;
            }
        }
    }
}

// =====================================================================
extern "C" void kernel_launch(void* const* d_in, const int* in_sizes, int n_in,
                              void* d_out, int out_size, void* d_ws, size_t ws_size,
                              hipStream_t stream) {
    const float* vectors = (const float*)d_in[0];
    const float* x       = (const float*)d_in[1];
    const float* V       = (const float*)d_in[2];
    const float* u       = (const float*)d_in[3];
    const float* m       = (const float*)d_in[4];
    const float* W_env   = (const float*)d_in[5];
    const float* W1      = (const float*)d_in[6];
    const float* W2      = (const float*)d_in[7];
    const float* W3      = (const float*)d_in[8];
    const float* W_out   = (const float*)d_in[9];
    const int*   senders = (const int*)d_in[10];

    const int E = in_sizes[4];   // 256000

    char*  wsb      = (char*)d_ws;
    float* node_cnt = (float*)d_ws;
    float* node_s   = node_cnt + NN_NODES;
    float* node_v   = node_s + (size_t)NN_NODES * 64;
    int* counts  = (int*)(wsb + WS_COUNTS);
    int* offsets = (int*)(wsb + WS_OFFSETS);
    int* cursor  = (int*)(wsb + WS_CURSOR);
    int* inv     = (int*)(wsb + WS_INV);
    int* order   = (int*)(wsb + WS_ORDER);
    float4* vecm = (float4*)(wsb + WS_VECM);
    char* xmb    = wsb + WS_XMB;

    float* out_x = (float*)d_out;
    float* out_v = out_x + (size_t)E * 128;
    char*  wvb   = (char*)out_v;   // sorted w scratch lives in out_v region

    k_wprep<<<128, 256, 0, stream>>>(W1, W2, W3, W_out, W_env, wsb);
    k_hist<<<(E + 1023) / 1024, 1024, 0, stream>>>(senders, counts, E);
    k_scan<<<1, 1024, 0, stream>>>(counts, offsets, cursor);
    k_binfill<<<(E + 1023) / 1024, 1024, 0, stream>>>(senders, vectors, m,
                                                      cursor, inv, order, vecm, E);
    k_env<<<(E + 127) / 128, 512, 0, stream>>>(x, m, wsb, inv, wvb, xmb, E);
    k_gather<<<(NN_NODES + 3) / 4, 256, 0, stream>>>(wvb, vecm, counts, offsets,
                                                     node_cnt, node_s, node_v);
    k_fuse<<<(E + 63) / 64, 512, 0, stream>>>(V, senders, node_cnt, node_s,
                                              node_v, wsb, xmb, u, order,
                                              out_x, out_v, INV_SILU_C, E);
}

// Round 14
// 410.674 us; speedup vs baseline: 1.1004x; 1.1004x over previous
//
#include <hip/hip_runtime.h>
#include <math.h>

typedef short bf16x8 __attribute__((ext_vector_type(8)));
typedef float f32x4 __attribute__((ext_vector_type(4)));

#define S128 0.08838834764831845f   /* 1/sqrt(128) */
#define S256I 0.0625f               /* 1/sqrt(256) */
#define NN_NODES 16000

// ws layout (bytes)
#define WS_COUNTS   16448000            /* int[16000] (node arrays occupy [0,16448000)) */
#define WS_OFFSETS  (WS_COUNTS + 64000)
#define WS_CURSOR   (WS_OFFSETS + 64000)
#define WS_INV      (WS_CURSOR + 64000) /* int[256000]: e -> sorted pos */
#define WS_W1 (WS_INV + 1024000)        /* W1T [128][256] bf16 unswizzled */
#define WS_W2 (WS_W1 + 65536)           /* W2T [128][128] bf16 unswizzled */
#define WS_W3 (WS_W2 + 32768)           /* W3T [128][128] bf16 unswizzled */
#define WS_WO (WS_W3 + 32768)           /* WoutT [64][128] bf16 PRE-SWIZZLED (LDS-staged) */
#define WS_WE (WS_WO + 16384)           /* WenvT [128][128] bf16 unswizzled (reg-loaded) */
#define WS_VECM (WS_WE + 32768)         /* float4[256000]: sorted (vx,vy,vz,m) */
#define WS_XMB  (WS_VECM + 4096000)     /* bf16 xm [E][128] linear, 65.5MB */

// ---- host-side constant: SILU_C exactly as the reference computes it ----
static float compute_inv_silu_c() {
    double sum = 0.0, prev = 0.0;
    const double dz = 24.0 / 100000.0;
    for (int i = 0; i <= 100000; ++i) {
        double z = -12.0 + dz * (double)i;
        double pdf = exp(-0.5 * z * z) * 0.3989422804014327;
        double s = z / (1.0 + exp(-z));
        double f = s * s * pdf;
        if (i) sum += 0.5 * (prev + f) * dz;
        prev = f;
    }
    return (float)(1.0 / sqrt(sum));
}
static const float INV_SILU_C = compute_inv_silu_c();

// ---- device helpers ----
__device__ __forceinline__ unsigned int packbf(float a, float b) {
    union { float f; unsigned int u; } ca, cb;
    ca.f = a; cb.f = b;
    unsigned int ua = ca.u + (0x7fffu + ((ca.u >> 16) & 1u));
    unsigned int ub = cb.u + (0x7fffu + ((cb.u >> 16) & 1u));
    return (ua >> 16) | (ub & 0xffff0000u);
}
__device__ __forceinline__ unsigned short bf16r(float v) {
    union { float f; unsigned int u; } c; c.f = v;
    return (unsigned short)((c.u + (0x7fffu + ((c.u >> 16) & 1u))) >> 16);
}
__device__ __forceinline__ float bflo(unsigned int u) { return __uint_as_float(u << 16); }
__device__ __forceinline__ float bfhi(unsigned int u) { return __uint_as_float(u & 0xffff0000u); }
// full-width swizzle for 256B-stride rows: spreads 16 rows across all bank groups
__device__ __forceinline__ int swz(int row, int b) { return b ^ ((row & 15) << 4); }
__device__ __forceinline__ float nsilu(float v, float ic) {
    return v / (1.0f + __expf(-v)) * ic;
}

// =====================================================================
// k_wprep: bf16-quantize + transpose weights into ws; zero counts[].
// =====================================================================
__global__ __launch_bounds__(256) void k_wprep(
    const float* __restrict__ W1, const float* __restrict__ W2,
    const float* __restrict__ W3, const float* __restrict__ Wout,
    const float* __restrict__ Wenv, char* __restrict__ wsb)
{
    const int t = blockIdx.x * 256 + threadIdx.x;   // 32768 threads
    if (t < NN_NODES) ((int*)(wsb + WS_COUNTS))[t] = 0;
    if (t < 32768) {  // W1T[128][256]
        int n = t & 127, k = t >> 7;
        *(unsigned short*)(wsb + WS_W1 + n * 512 + k * 2) =
            bf16r(W1[k * 128 + n] * S256I);
    }
    if (t < 16384) {  // W2T, W3T [128][128]
        int n = t & 127, k = t >> 7;
        *(unsigned short*)(wsb + WS_W2 + n * 256 + k * 2) =
            bf16r(W2[k * 128 + n] * S128);
        *(unsigned short*)(wsb + WS_W3 + n * 256 + k * 2) =
            bf16r(W3[k * 128 + n] * S128);
    }
    if (t < 16384) {  // WenvT[128][128], interleaved row perm (w0/w1 pairs)
        int j = t & 127, k = t >> 7;
        int c = (j & 1) ? 64 + (j >> 1) : (j >> 1);
        *(unsigned short*)(wsb + WS_WE + j * 256 + k * 2) =
            bf16r(Wenv[k * 128 + c] * S128);
    }
    if (t < 8192) {   // WoutT[64][128] pre-swizzled (full-width)
        int o = t & 63, uu = t >> 6;
        *(unsigned short*)(wsb + WS_WO + o * 256 + ((uu * 2) ^ ((o & 15) << 4))) =
            bf16r(Wout[uu * 64 + o] * S128);
    }
}

// =====================================================================
// sort-by-sender chain
// =====================================================================
__global__ __launch_bounds__(1024) void k_hist(
    const int* __restrict__ senders, int* __restrict__ counts, int E)
{
    const int e = blockIdx.x * 1024 + threadIdx.x;
    if (e < E) atomicAdd(&counts[senders[e]], 1);
}

__global__ __launch_bounds__(1024) void k_scan(
    const int* __restrict__ counts, int* __restrict__ offsets,
    int* __restrict__ cursor)
{
    __shared__ int part[1024];
    const int t = threadIdx.x;
    const int s0 = t * 16;
    const int s1 = (s0 + 16 < NN_NODES) ? s0 + 16 : NN_NODES;
    int s = 0;
    for (int i = s0; i < s1; ++i) s += counts[i];
    part[t] = s;
    __syncthreads();
    for (int off = 1; off < 1024; off <<= 1) {
        int v = part[t];
        if (t >= off) v += part[t - off];
        __syncthreads();
        part[t] = v;
        __syncthreads();
    }
    int run = t ? part[t - 1] : 0;
    for (int i = s0; i < s1; ++i) {
        offsets[i] = run; cursor[i] = run; run += counts[i];
    }
}

__global__ __launch_bounds__(1024) void k_binfill(
    const int* __restrict__ senders, const float* __restrict__ vectors,
    const float* __restrict__ m, int* __restrict__ cursor,
    int* __restrict__ inv, float4* __restrict__ vecm, int E)
{
    const int e = blockIdx.x * 1024 + threadIdx.x;
    if (e < E) {
        const int p = atomicAdd(&cursor[senders[e]], 1);
        inv[e] = p;
        float4 vm;
        vm.x = vectors[(size_t)e * 3 + 0];
        vm.y = vectors[(size_t)e * 3 + 1];
        vm.z = vectors[(size_t)e * 3 + 2];
        vm.w = m[e];
        vecm[p] = vm;
    }
}

// =====================================================================
// k_env: w = (x*m) @ WenvT via MFMA. 128 edges/block, 32KB LDS.
// Exports bf16 xm (linear) for k_fuse; writes w rows at SORTED positions.
// =====================================================================
__global__ __launch_bounds__(512) void k_env(
    const float* __restrict__ x, const float* __restrict__ m,
    const char* __restrict__ wsb, const int* __restrict__ inv,
    char* __restrict__ wout, char* __restrict__ xmb, int E)
{
    __shared__ char lds[32768];  // xm [128][256B] swz; reused for bf16 results
    const int tid = threadIdx.x, l = tid & 63, wid = tid >> 6;
    const int lr = l & 15, lg = l >> 4;
    const int n0 = wid * 16;

    // WenvT fragments for this wave's 16 columns (loop-invariant)
    bf16x8 B[4];
    #pragma unroll
    for (int kk = 0; kk < 4; ++kk)
        B[kk] = *(const bf16x8*)(wsb + WS_WE + (n0 + lr) * 256 + kk * 64 + lg * 16);

    const int eb = blockIdx.x * 128;
    {   // xm tile: 4 threads/edge
        const int el = tid >> 2, q = tid & 3;
        const int e = eb + el;
        if (e < E) {
            const float mv = m[e];
            const float4* xp = (const float4*)&x[(size_t)e * 128 + q * 32];
            #pragma unroll
            for (int j = 0; j < 4; ++j) {
                float4 A = xp[2 * j], Bv = xp[2 * j + 1];
                int4 w;
                w.x = packbf(A.x * mv, A.y * mv); w.y = packbf(A.z * mv, A.w * mv);
                w.z = packbf(Bv.x * mv, Bv.y * mv); w.w = packbf(Bv.z * mv, Bv.w * mv);
                *(int4*)(lds + el * 256 + swz(el, q * 64 + j * 16)) = w;
            }
        } else {
            const int4 z = {0, 0, 0, 0};
            #pragma unroll
            for (int j = 0; j < 4; ++j)
                *(int4*)(lds + el * 256 + swz(el, q * 64 + j * 16)) = z;
        }
    }
    __syncthreads();

    {   // export xm bf16 (linear) for k_fuse
        const int el = tid >> 2, q = tid & 3;
        const int e = eb + el;
        if (e < E) {
            int4* d = (int4*)(xmb + (size_t)e * 256 + q * 64);
            #pragma unroll
            for (int j = 0; j < 4; ++j)
                d[j] = *(int4*)(lds + el * 256 + swz(el, q * 64 + j * 16));
        }
    }

    f32x4 acc[8];
    #pragma unroll
    for (int a = 0; a < 8; ++a) acc[a] = (f32x4){0.f, 0.f, 0.f, 0.f};

    #pragma unroll
    for (int kk = 0; kk < 4; ++kk) {
        const int kb = kk * 64 + lg * 16;
        #pragma unroll
        for (int mt = 0; mt < 8; ++mt) {
            const int row = mt * 16 + lr;
            bf16x8 a = *(const bf16x8*)(lds + row * 256 + swz(row, kb));
            acc[mt] = __builtin_amdgcn_mfma_f32_16x16x32_bf16(a, B[kk], acc[mt], 0, 0, 0);
        }
    }
    __syncthreads();   // all A-reads done; reuse buffer for results

    #pragma unroll
    for (int mt = 0; mt < 8; ++mt)
        #pragma unroll
        for (int r = 0; r < 4; ++r) {
            const int row = mt * 16 + lg * 4 + r;
            *(unsigned short*)(lds + row * 256 + swz(row, (n0 + lr) * 2)) =
                bf16r(acc[mt][r]);
        }
    __syncthreads();

    {   // copy-out to SORTED position p = inv[e]
        const int el = tid >> 2, q = tid & 3;
        const int e = eb + el;
        if (e < E) {
            const int p = inv[e];
            int4* d = (int4*)(wout + (size_t)p * 256 + q * 64);
            #pragma unroll
            for (int j = 0; j < 4; ++j)
                d[j] = *(int4*)(lds + el * 256 + swz(el, q * 64 + j * 16));
        }
    }
}

// =====================================================================
// k_gather: one wave per node; STREAMING reads of sorted w rows and
// vecm; write node accumulators once (no atomics).
// =====================================================================
__global__ __launch_bounds__(256) void k_gather(
    const char* __restrict__ wvb, const float4* __restrict__ vecm,
    const int* __restrict__ counts, const int* __restrict__ offsets,
    float* __restrict__ node_cnt, float* __restrict__ node_s,
    float* __restrict__ node_v)
{
    const int l = threadIdx.x & 63, wid = threadIdx.x >> 6;
    const int n = blockIdx.x * 4 + wid;
    if (n >= NN_NODES) return;
    const int cnt = counts[n], base = offsets[n];

    float as = 0.f, a0 = 0.f, a1 = 0.f, a2 = 0.f, am = 0.f;
    #pragma unroll 4
    for (int i = 0; i < cnt; ++i) {
        const unsigned int wv =
            *(const unsigned int*)(wvb + (size_t)(base + i) * 256 + l * 4);
        const float4 vm = vecm[base + i];
        const float rn = 1.7320508075688772f /
                         sqrtf(vm.x * vm.x + vm.y * vm.y + vm.z * vm.z);
        const float w0 = bflo(wv) * vm.w;
        const float c1 = bfhi(wv) * vm.w * rn;
        as += w0; am += vm.w;
        a0 += c1 * vm.x; a1 += c1 * vm.y; a2 += c1 * vm.z;
    }
    if (l == 0) node_cnt[n] = am;
    node_s[(size_t)n * 64 + l] = as;
    float* nv = &node_v[((size_t)n * 64 + l) * 3];
    nv[0] = a0; nv[1] = a1; nv[2] = a2;
}

// =====================================================================
// k_fuse: merged prep_vout + MLP. 64 edges/block, 512 threads, 80KB LDS.
// Phase A hoists the 8 senders[] loads (8 VGPRs only — R12's 64-float
// split spilled); node loads then become address-ready and overlap.
// LDS map: [0:48K) vin -> Vout f32 stage -> {xcatLo,h@32K} -> g@0 -> out
//          [48K:64K) WoutT (pre-swizzled)   [64K:80K) xcatHi (s_a|s_b)
// =====================================================================
__global__ __launch_bounds__(512, 4) void k_fuse(
    const float* __restrict__ V, const int* __restrict__ senders,
    const float* __restrict__ node_cnt, const float* __restrict__ node_s,
    const float* __restrict__ node_v, const char* __restrict__ wsb,
    const char* __restrict__ xmb, const float* __restrict__ ug,
    float* __restrict__ out_x, float* __restrict__ out_v,
    float inv_c, int E)
{
    __shared__ char lds[81920];
    const int tid = threadIdx.x, l = tid & 63, wid = tid >> 6;
    const int lr = l & 15, lg = l >> 4;
    const int eb = blockIdx.x * 64;

    {   // stage WoutT (pre-swizzled) -> [48K:64K)
        const int4* src = (const int4*)(wsb + WS_WO);
        ((int4*)(lds + 49152))[tid * 2]     = src[tid * 2];
        ((int4*)(lds + 49152))[tid * 2 + 1] = src[tid * 2 + 1];
    }

    // hoisted sender indices: 8 independent loads, one latency round
    int sn[8];
    #pragma unroll
    for (int i = 0; i < 8; ++i) {
        const int e = eb + wid * 8 + i;
        sn[i] = (e < E) ? senders[e] : 0;
    }

    // ---- phase A: per-edge gather; vin tile + s_a/s_b -> xcatHi stash ----
    #pragma unroll 2
    for (int i = 0; i < 8; ++i) {
        const int el = wid * 8 + i;
        const int e  = eb + el;
        float Vs = 0.f, Vv0 = 0.f, Vv1 = 0.f, Vv2 = 0.f;
        float wYs = 0.f, wv0 = 0.f, wv1 = 0.f, wv2 = 0.f;
        if (e < E) {
            Vs = V[(size_t)e * 256 + l];
            const float* vp = &V[(size_t)e * 256 + 64 + l * 3];
            Vv0 = vp[0]; Vv1 = vp[1]; Vv2 = vp[2];
            const float rden = 1.0f / (node_cnt[sn[i]] + 1e-5f);
            wYs = node_s[(size_t)sn[i] * 64 + l] * rden;
            const float* nvp = &node_v[((size_t)sn[i] * 64 + l) * 3];
            wv0 = nvp[0] * rden; wv1 = nvp[1] * rden; wv2 = nvp[2] * rden;
        }
        // s_a/s_b straight into phase-B xcatHi layout (swizzled, 256B rows)
        *(unsigned short*)(lds + 65536 + el * 256 + swz(el, l * 2)) =
            bf16r(wYs * Vs);
        *(unsigned short*)(lds + 65536 + el * 256 + swz(el, 128 + l * 2)) =
            bf16r((wv0 * Vv0 + wv1 * Vv1 + wv2 * Vv2) * 0.57735026918962576f);
        const float vvk[3] = {Vv0, Vv1, Vv2};
        const float wvk[3] = {wv0, wv1, wv2};
        #pragma unroll
        for (int k = 0; k < 3; ++k) {
            const int row = el * 3 + k;
            *(unsigned short*)(lds + row * 256 + swz(row, l * 2))       = bf16r(wYs * vvk[k]);
            *(unsigned short*)(lds + row * 256 + swz(row, 128 + l * 2)) = bf16r(wvk[k] * Vs);
        }
    }
    __syncthreads();

    // ---- V_out GEMM: waves 4x2; wave = 3 m-tiles x 2 n-tiles ----
    {
        const int wm = wid & 3, wn = wid >> 2;
        const int m0 = wm * 48, n0v = wn * 32;
        f32x4 acc[3][2];
        #pragma unroll
        for (int a = 0; a < 3; ++a)
            #pragma unroll
            for (int b = 0; b < 2; ++b) acc[a][b] = (f32x4){0.f, 0.f, 0.f, 0.f};

        #pragma unroll
        for (int kk = 0; kk < 4; ++kk) {
            const int kb = kk * 64 + lg * 16;
            bf16x8 a0 = *(const bf16x8*)(lds + (m0 + lr) * 256      + swz(m0 + lr, kb));
            bf16x8 a1 = *(const bf16x8*)(lds + (m0 + 16 + lr) * 256 + swz(m0 + 16 + lr, kb));
            bf16x8 a2 = *(const bf16x8*)(lds + (m0 + 32 + lr) * 256 + swz(m0 + 32 + lr, kb));
            bf16x8 b0 = *(const bf16x8*)(lds + 49152 + (n0v + lr) * 256      + swz(n0v + lr, kb));
            bf16x8 b1 = *(const bf16x8*)(lds + 49152 + (n0v + 16 + lr) * 256 + swz(n0v + 16 + lr, kb));
            acc[0][0] = __builtin_amdgcn_mfma_f32_16x16x32_bf16(a0, b0, acc[0][0], 0, 0, 0);
            acc[0][1] = __builtin_amdgcn_mfma_f32_16x16x32_bf16(a0, b1, acc[0][1], 0, 0, 0);
            acc[1][0] = __builtin_amdgcn_mfma_f32_16x16x32_bf16(a1, b0, acc[1][0], 0, 0, 0);
            acc[1][1] = __builtin_amdgcn_mfma_f32_16x16x32_bf16(a1, b1, acc[1][1], 0, 0, 0);
            acc[2][0] = __builtin_amdgcn_mfma_f32_16x16x32_bf16(a2, b0, acc[2][0], 0, 0, 0);
            acc[2][1] = __builtin_amdgcn_mfma_f32_16x16x32_bf16(a2, b1, acc[2][1], 0, 0, 0);
        }
        __syncthreads();   // all vin reads done; reuse [0:48K) as f32 stage

        #pragma unroll
        for (int mt = 0; mt < 3; ++mt)
            #pragma unroll
            for (int nt = 0; nt < 2; ++nt)
                #pragma unroll
                for (int r = 0; r < 4; ++r) {
                    const int mm = m0 + mt * 16 + lg * 4 + r;
                    const int el2 = mm / 3, kd = mm - el2 * 3;
                    const int o = n0v + nt * 16 + lr;
                    *(float*)(lds + el2 * 768 + (o * 3 + kd) * 4) = acc[mt][nt][r];
                }
    }
    __syncthreads();
    if (eb + 64 <= E) {   // coalesced 48KB copy-out
        const int4* s = (const int4*)lds;
        int4* d = (int4*)(out_v + (size_t)eb * 192);
        #pragma unroll
        for (int j = 0; j < 6; ++j) d[tid * 6 + j] = s[tid * 6 + j];
    } else {
        for (int idx = tid; idx < 64 * 192; idx += 512) {
            const int el2 = idx / 192;
            if (eb + el2 < E)
                out_v[(size_t)(eb + el2) * 192 + (idx % 192)] = *(float*)(lds + idx * 4);
        }
    }
    __syncthreads();   // copy-out reads done; [0:48K) free for phase B

    // ---- phase B: MLP ----
    // xcatLo [64][256B] @0 (xm); xcatHi @64K (already built); h @32K
    const int n0 = wid * 16;
    bf16x8 B1[8];
    #pragma unroll
    for (int kk = 0; kk < 8; ++kk)
        B1[kk] = *(const bf16x8*)(wsb + WS_W1 + (n0 + lr) * 512 + kk * 64 + lg * 16);

    {   // xm -> xcatLo: 8 threads/edge
        const int el = tid >> 3, q = tid & 7;
        const int e = eb + el;
        int4 x0, x1;
        if (e < E) {
            const int4* xp = (const int4*)(xmb + (size_t)e * 256 + q * 32);
            x0 = xp[0]; x1 = xp[1];
        } else {
            x0 = (int4){0, 0, 0, 0}; x1 = (int4){0, 0, 0, 0};
        }
        *(int4*)(lds + el * 256 + swz(el, q * 32))      = x0;
        *(int4*)(lds + el * 256 + swz(el, q * 32 + 16)) = x1;
    }
    __syncthreads();

    // stage 1: xcat[64x256] @ W1T  (cols 0-127 @0, cols 128-255 @64K)
    f32x4 a1[4];
    #pragma unroll
    for (int a = 0; a < 4; ++a) a1[a] = (f32x4){0.f, 0.f, 0.f, 0.f};
    #pragma unroll
    for (int kk = 0; kk < 8; ++kk) {
        const int base = (kk < 4) ? 0 : 65536;
        const int kb = (kk & 3) * 64 + lg * 16;
        #pragma unroll
        for (int mt = 0; mt < 4; ++mt) {
            const int row = mt * 16 + lr;
            bf16x8 a = *(const bf16x8*)(lds + base + row * 256 + swz(row, kb));
            a1[mt] = __builtin_amdgcn_mfma_f32_16x16x32_bf16(a, B1[kk], a1[mt], 0, 0, 0);
        }
    }

    bf16x8 B2[4], B3[4];
    #pragma unroll
    for (int kk = 0; kk < 4; ++kk) {
        B2[kk] = *(const bf16x8*)(wsb + WS_W2 + (n0 + lr) * 256 + kk * 64 + lg * 16);
        B3[kk] = *(const bf16x8*)(wsb + WS_W3 + (n0 + lr) * 256 + kk * 64 + lg * 16);
    }

    // write h (bf16) to [32K:48K)
    #pragma unroll
    for (int mt = 0; mt < 4; ++mt)
        #pragma unroll
        for (int r = 0; r < 4; ++r) {
            const int row = mt * 16 + lg * 4 + r;
            *(unsigned short*)(lds + 32768 + row * 256 + swz(row, (n0 + lr) * 2)) =
                bf16r(nsilu(a1[mt][r], inv_c));
        }
    __syncthreads();

    // stage 2: h @ W2T
    f32x4 a2[4];
    #pragma unroll
    for (int a = 0; a < 4; ++a) a2[a] = (f32x4){0.f, 0.f, 0.f, 0.f};
    #pragma unroll
    for (int kk = 0; kk < 4; ++kk) {
        const int kb = kk * 64 + lg * 16;
        #pragma unroll
        for (int mt = 0; mt < 4; ++mt) {
            const int row = mt * 16 + lr;
            bf16x8 a = *(const bf16x8*)(lds + 32768 + row * 256 + swz(row, kb));
            a2[mt] = __builtin_amdgcn_mfma_f32_16x16x32_bf16(a, B2[kk], a2[mt], 0, 0, 0);
        }
    }
    // write g (bf16) into [0:16K) — xcatLo reads finished (h barrier)
    #pragma unroll
    for (int mt = 0; mt < 4; ++mt)
        #pragma unroll
        for (int r = 0; r < 4; ++r) {
            const int row = mt * 16 + lg * 4 + r;
            *(unsigned short*)(lds + row * 256 + swz(row, (n0 + lr) * 2)) =
                bf16r(nsilu(a2[mt][r], inv_c));
        }
    __syncthreads();

    // stage 3: g @ W3T
    f32x4 a3[4];
    #pragma unroll
    for (int a = 0; a < 4; ++a) a3[a] = (f32x4){0.f, 0.f, 0.f, 0.f};
    #pragma unroll
    for (int kk = 0; kk < 4; ++kk) {
        const int kb = kk * 64 + lg * 16;
        #pragma unroll
        for (int mt = 0; mt < 4; ++mt) {
            const int row = mt * 16 + lr;
            bf16x8 a = *(const bf16x8*)(lds + row * 256 + swz(row, kb));
            a3[mt] = __builtin_amdgcn_mfma_f32_16x16x32_bf16(a, B3[kk], a3[mt], 0, 0, 0);
        }
    }
    __syncthreads();   // all g reads done; reuse [0:32K) for f32 out tiles

    // out staging: cols 0-63 -> outLo @0, 64-127 -> outHi @16K (256B rows)
    {
        const int base = (n0 < 64) ? 0 : 16384;
        const int colb = n0 & 63;
        #pragma unroll
        for (int mt = 0; mt < 4; ++mt)
            #pragma unroll
            for (int r = 0; r < 4; ++r) {
                const int row = mt * 16 + lg * 4 + r;
                *(float*)(lds + base + row * 256 + swz(row, (colb + lr) * 4)) = a3[mt][r];
            }
    }
    __syncthreads();

    {   // coalesced copy-out with u scaling
        const int el = tid >> 3, q = tid & 7;
        const int e = eb + el;
        if (e < E) {
            const float uu = ug[e];
            #pragma unroll
            for (int j = 0; j < 4; ++j) {
                const int b = q * 64 + j * 16;       // byte in 512B logical row
                const int base = (b < 256) ? 0 : 16384;
                int4 v = *(int4*)(lds + base + el * 256 + swz(el, b & 255));
                float4 f;
                f.x = __int_as_float(v.x) * uu; f.y = __int_as_float(v.y) * uu;
                f.z = __int_as_float(v.z) * uu; f.w = __int_as_float(v.w) * uu;
                *(float4*)(&out_x[(size_t)e * 128 + q * 16 + j * 4]) = f;
            }
        }
    }
}

// =====================================================================
extern "C" void kernel_launch(void* const* d_in, const int* in_sizes, int n_in,
                              void* d_out, int out_size, void* d_ws, size_t ws_size,
                              hipStream_t stream) {
    const float* vectors = (const float*)d_in[0];
    const float* x       = (const float*)d_in[1];
    const float* V       = (const float*)d_in[2];
    const float* u       = (const float*)d_in[3];
    const float* m       = (const float*)d_in[4];
    const float* W_env   = (const float*)d_in[5];
    const float* W1      = (const float*)d_in[6];
    const float* W2      = (const float*)d_in[7];
    const float* W3      = (const float*)d_in[8];
    const float* W_out   = (const float*)d_in[9];
    const int*   senders = (const int*)d_in[10];

    const int E = in_sizes[4];   // 256000

    char*  wsb      = (char*)d_ws;
    float* node_cnt = (float*)d_ws;
    float* node_s   = node_cnt + NN_NODES;
    float* node_v   = node_s + (size_t)NN_NODES * 64;
    int* counts  = (int*)(wsb + WS_COUNTS);
    int* offsets = (int*)(wsb + WS_OFFSETS);
    int* cursor  = (int*)(wsb + WS_CURSOR);
    int* inv     = (int*)(wsb + WS_INV);
    float4* vecm = (float4*)(wsb + WS_VECM);
    char* xmb    = wsb + WS_XMB;

    float* out_x = (float*)d_out;
    float* out_v = out_x + (size_t)E * 128;
    char*  wvb   = (char*)out_v;   // sorted w scratch lives in out_v region

    k_wprep<<<128, 256, 0, stream>>>(W1, W2, W3, W_out, W_env, wsb);
    k_hist<<<(E + 1023) / 1024, 1024, 0, stream>>>(senders, counts, E);
    k_scan<<<1, 1024, 0, stream>>>(counts, offsets, cursor);
    k_binfill<<<(E + 1023) / 1024, 1024, 0, stream>>>(senders, vectors, m,
                                                      cursor, inv, vecm, E);
    k_env<<<(E + 127) / 128, 512, 0, stream>>>(x, m, wsb, inv, wvb, xmb, E);
    k_gather<<<(NN_NODES + 3) / 4, 256, 0, stream>>>(wvb, vecm, counts, offsets,
                                                     node_cnt, node_s, node_v);
    k_fuse<<<(E + 63) / 64, 512, 0, stream>>>(V, senders, node_cnt, node_s,
                                              node_v, wsb, xmb, u,
                                              out_x, out_v, INV_SILU_C, E);
}